// Round 1
// baseline (355.692 us; speedup 1.0000x reference)
//
#include <hip/hip_runtime.h>
#include <math.h>

// Problem constants (from reference): B=32, C=3, H=W=512, window 11, sigma 1.5
#define H 512
#define W 512
#define WS 11
#define OUT_H 502   // 512 - 11 + 1
#define OUT_W 502
#define C1 1.0e-4f  // (0.01*1)^2
#define C2 9.0e-4f  // (0.03*1)^2

// Tile config
#define TW 54       // output tile width
#define TH 32       // output tile height
#define NCOL 64     // TW + 10 input columns needed
#define NCOLP 68    // padded LDS row stride (mult of 4 for float4, room for 20-float reads)
#define RCH 8       // rows per vertical-pass chunk (4 chunks * 64 cols = 256 tasks)

__device__ __forceinline__ void hconv8(const float* __restrict__ row, int x0,
                                       const float g[11], float res[8]) {
    // row is 16B-aligned at x0 (x0 multiple of 8). Load 20 floats, 8 sliding 11-tap dots.
    float vals[20];
    const float4* r4 = reinterpret_cast<const float4*>(row + x0);
#pragma unroll
    for (int i = 0; i < 5; ++i) {
        float4 f = r4[i];
        vals[4*i+0] = f.x; vals[4*i+1] = f.y; vals[4*i+2] = f.z; vals[4*i+3] = f.w;
    }
#pragma unroll
    for (int xi = 0; xi < 8; ++xi) {
        float acc = 0.f;
#pragma unroll
        for (int t = 0; t < 11; ++t) acc = fmaf(g[t], vals[xi + t], acc);
        res[xi] = acc;
    }
}

__global__ __launch_bounds__(256) void ssim_kernel(const float* __restrict__ img1,
                                                   const float* __restrict__ img2,
                                                   float* __restrict__ out) {
    // 5 vertically-convolved quantities staged in LDS
    __shared__ float v1s [TH][NCOLP];
    __shared__ float v2s [TH][NCOLP];
    __shared__ float v11s[TH][NCOLP];
    __shared__ float v22s[TH][NCOLP];
    __shared__ float v12s[TH][NCOLP];
    __shared__ float wsum[4];

    const int tid = threadIdx.x;

    // Gaussian weights (constant-folded expf), normalized
    float g[11];
    {
        float s = 0.f;
#pragma unroll
        for (int i = 0; i < 11; ++i) {
            float d = (float)(i - 5);
            g[i] = expf(-d * d * (1.0f / 4.5f));
            s += g[i];
        }
        float inv = 1.0f / s;
#pragma unroll
        for (int i = 0; i < 11; ++i) g[i] *= inv;
    }

    const int X0 = blockIdx.x * TW;
    const int Y0 = blockIdx.y * TH;
    const int plane = blockIdx.z;              // b*3 + c
    const size_t pbase = (size_t)plane * (H * W);
    const float* __restrict__ p1 = img1 + pbase;
    const float* __restrict__ p2 = img2 + pbase;

    // ---------------- vertical pass: global -> LDS ----------------
    {
        const int c = tid & 63;          // column 0..63
        const int chunk = tid >> 6;      // 0..3
        const int y0 = chunk * RCH;
        const int gx = X0 + c;
        const bool colok = (gx < W);

        float am1[RCH], am2[RCH], a11[RCH], a22[RCH], a12[RCH];
#pragma unroll
        for (int k = 0; k < RCH; ++k) am1[k] = am2[k] = a11[k] = a22[k] = a12[k] = 0.f;

#pragma unroll
        for (int j = 0; j < RCH + 10; ++j) {
            const int gy = Y0 + y0 + j;
            float x1 = 0.f, x2 = 0.f;
            if (colok && gy < H) {
                const size_t idx = (size_t)gy * W + gx;
                x1 = p1[idx];
                x2 = p2[idx];
            }
            const float q11 = x1 * x1, q22 = x2 * x2, q12 = x1 * x2;
#pragma unroll
            for (int k = 0; k < RCH; ++k) {
                const int t = j - k;
                if (t >= 0 && t < 11) {   // constant-folds after unroll
                    const float w = g[t];
                    am1[k] = fmaf(w, x1,  am1[k]);
                    am2[k] = fmaf(w, x2,  am2[k]);
                    a11[k] = fmaf(w, q11, a11[k]);
                    a22[k] = fmaf(w, q22, a22[k]);
                    a12[k] = fmaf(w, q12, a12[k]);
                }
            }
        }
#pragma unroll
        for (int k = 0; k < RCH; ++k) {
            v1s [y0 + k][c] = am1[k];
            v2s [y0 + k][c] = am2[k];
            v11s[y0 + k][c] = a11[k];
            v22s[y0 + k][c] = a22[k];
            v12s[y0 + k][c] = a12[k];
        }
    }
    __syncthreads();

    // ---------------- horizontal pass + SSIM + local sum ----------------
    float lsum = 0.f;
    if (tid < 224) {                      // 32 rows * 7 x-groups of 8
        const int y  = tid / 7;
        const int jj = tid - y * 7;
        const int x0 = jj * 8;            // 0,8,...,48 (16B aligned)

        float mu1[8], mu2[8], s11[8], s22[8], s12[8];
        hconv8(&v1s [y][0], x0, g, mu1);
        hconv8(&v2s [y][0], x0, g, mu2);
        hconv8(&v11s[y][0], x0, g, s11);
        hconv8(&v22s[y][0], x0, g, s22);
        hconv8(&v12s[y][0], x0, g, s12);

        const int oy = Y0 + y;
#pragma unroll
        for (int xi = 0; xi < 8; ++xi) {
            const int lx = x0 + xi;
            const int ox = X0 + lx;
            if (lx < TW && ox < OUT_W && oy < OUT_H) {
                const float m1 = mu1[xi], m2 = mu2[xi];
                const float m1s = m1 * m1, m2s = m2 * m2, m12 = m1 * m2;
                const float sig1  = s11[xi] - m1s;
                const float sig2  = s22[xi] - m2s;
                const float sig12 = s12[xi] - m12;
                const float num = (2.f * m12 + C1) * (2.f * sig12 + C2);
                const float den = (m1s + m2s + C1) * (sig1 + sig2 + C2);
                lsum += num / den;
            }
        }
    }

    // ---------------- block reduce + atomic ----------------
#pragma unroll
    for (int off = 32; off > 0; off >>= 1) lsum += __shfl_down(lsum, off, 64);
    if ((tid & 63) == 0) wsum[tid >> 6] = lsum;
    __syncthreads();
    if (tid == 0) {
        const float inv_count = 1.0f / (3.0f * (float)OUT_H * (float)OUT_W);
        const float total = (wsum[0] + wsum[1] + wsum[2] + wsum[3]) * inv_count;
        atomicAdd(&out[plane / 3], total);
    }
}

__global__ void zero_out(float* out, int n) {
    int i = threadIdx.x + blockIdx.x * blockDim.x;
    if (i < n) out[i] = 0.f;
}

extern "C" void kernel_launch(void* const* d_in, const int* in_sizes, int n_in,
                              void* d_out, int out_size, void* d_ws, size_t ws_size,
                              hipStream_t stream) {
    const float* img1 = (const float*)d_in[0];
    const float* img2 = (const float*)d_in[1];
    float* out = (float*)d_out;

    zero_out<<<1, 64, 0, stream>>>(out, out_size);

    const int nplanes = in_sizes[0] / (H * W);          // 96
    dim3 grid((OUT_W + TW - 1) / TW,                    // 10
              (OUT_H + TH - 1) / TH,                    // 16
              nplanes);
    ssim_kernel<<<grid, 256, 0, stream>>>(img1, img2, out);
}

// Round 2
// 262.257 us; speedup vs baseline: 1.3563x; 1.3563x over previous
//
#include <hip/hip_runtime.h>
#include <math.h>

// B=32, C=3, H=W=512, window 11, sigma 1.5, VALID conv -> 502x502
#define H 512
#define W 512
#define OUT_H 502
#define OUT_W 502
#define C1c 1.0e-4f   // (0.01*1)^2
#define C2c 9.0e-4f   // (0.03*1)^2

#define TH 56             // output rows per block
#define NR (TH + 10)      // 66 input rows processed (66 = 6*11, phase-aligned)
#define NCOLS 256         // output columns per block (one per thread)
#define HALO 10

// Row-streaming SSIM:
//  - each thread owns one output column; block covers 256 cols (+10 halo)
//  - per input row: stage (x1,x2) pairs in a 2-slot LDS ring, horizontal conv
//    (products computed on the fly), then scatter into 11 phase-unrolled
//    vertical partial-output accumulators (registers).
//  - 1-row register prefetch hides global-load latency behind a row of compute.
__global__ __launch_bounds__(256, 4) void ssim_kernel(const float* __restrict__ img1,
                                                      const float* __restrict__ img2,
                                                      float* __restrict__ out) {
    __shared__ float2 ring[2][NCOLS + HALO];   // (x1,x2) interleaved pairs
    __shared__ float wsum[4];

    const int tid = threadIdx.x;

    // Gaussian weights (constant-folded expf, normalized) — matches reference
    float g[11];
    {
        float s = 0.f;
#pragma unroll
        for (int i = 0; i < 11; ++i) {
            float d = (float)(i - 5);
            g[i] = expf(-d * d * (1.0f / 4.5f));
            s += g[i];
        }
        float inv = 1.0f / s;
#pragma unroll
        for (int i = 0; i < 11; ++i) g[i] *= inv;
    }

    const int X0 = blockIdx.x * NCOLS;
    const int Y0 = blockIdx.y * TH;
    const int plane = blockIdx.z;              // b*3 + c
    const size_t pbase = (size_t)plane * (H * W);
    const float* __restrict__ p1 = img1 + pbase;
    const float* __restrict__ p2 = img2 + pbase;

    const int gx = X0 + tid;                         // < 512 always
    const int hx = min(X0 + NCOLS + tid, W - 1);     // halo col (tid<10), clamped

    // 11 phase slots of vertical partial sums for each of 5 quantities
    float acc0[11], acc1[11], acc2[11], acc3[11], acc4[11];
#pragma unroll
    for (int i = 0; i < 11; ++i) { acc0[i]=0.f; acc1[i]=0.f; acc2[i]=0.f; acc3[i]=0.f; acc4[i]=0.f; }

    float lsum = 0.f;

    // prime prefetch (row r = 0)
    {
        const size_t rowoff = (size_t)min(Y0, H - 1) * W;
        // nothing else
    }
    int gy0 = min(Y0, H - 1);
    float a1 = p1[(size_t)gy0 * W + gx];
    float a2 = p2[(size_t)gy0 * W + gx];
    float b1 = 0.f, b2 = 0.f;
    if (tid < HALO) { b1 = p1[(size_t)gy0 * W + hx]; b2 = p2[(size_t)gy0 * W + hx]; }

#pragma unroll 1
    for (int rb = 0; rb < NR; rb += 11) {
#pragma unroll
        for (int p = 0; p < 11; ++p) {
            const int r = rb + p;
            const int slot = r & 1;

            // stage current row into the ring
            ring[slot][tid] = make_float2(a1, a2);
            if (tid < HALO) ring[slot][NCOLS + tid] = make_float2(b1, b2);

            // prefetch next row into registers (clamped; last one harmless)
            {
                const int gy = min(Y0 + r + 1, H - 1);
                const size_t rowoff = (size_t)gy * W;
                a1 = p1[rowoff + gx];
                a2 = p2[rowoff + gx];
                if (tid < HALO) { b1 = p1[rowoff + hx]; b2 = p2[rowoff + hx]; }
            }

            __syncthreads();

            // horizontal conv of the 5 quantities (products on the fly)
            float h0 = 0.f, h1 = 0.f, h2 = 0.f, h3 = 0.f, h4 = 0.f;
            const float2* rp = &ring[slot][tid];
#pragma unroll
            for (int t = 0; t < 11; ++t) {
                const float2 v = rp[t];               // ds_read_b64, offset t*8
                const float w = g[t];
                h0 = fmaf(w, v.x,       h0);
                h1 = fmaf(w, v.y,       h1);
                h2 = fmaf(w, v.x * v.x, h2);
                h3 = fmaf(w, v.y * v.y, h3);
                h4 = fmaf(w, v.x * v.y, h4);
            }

            // vertical scatter: row r contributes weight g[(p-a) mod 11] to slot a
#pragma unroll
            for (int a = 0; a < 11; ++a) {
                const float w = g[(p - a + 11) % 11];  // compile-time index
                acc0[a] = fmaf(w, h0, acc0[a]);
                acc1[a] = fmaf(w, h1, acc1[a]);
                acc2[a] = fmaf(w, h2, acc2[a]);
                acc3[a] = fmaf(w, h3, acc3[a]);
                acc4[a] = fmaf(w, h4, acc4[a]);
            }

            // output row oy = Y0 + r - 10 completes in slot e = (p+1)%11
            const int e = (p + 1) % 11;
            if (r >= 10) {
                const int oy = Y0 + r - 10;
                const float m1 = acc0[e], m2 = acc1[e];
                const float m1s = m1 * m1, m2s = m2 * m2, m12 = m1 * m2;
                const float sig1  = acc2[e] - m1s;
                const float sig2  = acc3[e] - m2s;
                const float sig12 = acc4[e] - m12;
                const float num = (2.f * m12 + C1c) * (2.f * sig12 + C2c);
                const float den = (m1s + m2s + C1c) * (sig1 + sig2 + C2c);
                const float v = num * __builtin_amdgcn_rcpf(den);
                if (gx < OUT_W && oy < OUT_H) lsum += v;
            }
            acc0[e] = 0.f; acc1[e] = 0.f; acc2[e] = 0.f; acc3[e] = 0.f; acc4[e] = 0.f;
        }
    }

    // block reduce + one atomic per block
#pragma unroll
    for (int off = 32; off > 0; off >>= 1) lsum += __shfl_down(lsum, off, 64);
    if ((tid & 63) == 0) wsum[tid >> 6] = lsum;
    __syncthreads();
    if (tid == 0) {
        const float inv_count = 1.0f / (3.0f * (float)OUT_H * (float)OUT_W);
        const float total = (wsum[0] + wsum[1] + wsum[2] + wsum[3]) * inv_count;
        atomicAdd(&out[plane / 3], total);
    }
}

__global__ void zero_out(float* out, int n) {
    int i = threadIdx.x + blockIdx.x * blockDim.x;
    if (i < n) out[i] = 0.f;
}

extern "C" void kernel_launch(void* const* d_in, const int* in_sizes, int n_in,
                              void* d_out, int out_size, void* d_ws, size_t ws_size,
                              hipStream_t stream) {
    const float* img1 = (const float*)d_in[0];
    const float* img2 = (const float*)d_in[1];
    float* out = (float*)d_out;

    zero_out<<<1, 64, 0, stream>>>(out, out_size);

    const int nplanes = in_sizes[0] / (H * W);          // 96
    dim3 grid(W / NCOLS,                                // 2
              (OUT_H + TH - 1) / TH,                    // 9
              nplanes);
    ssim_kernel<<<grid, 256, 0, stream>>>(img1, img2, out);
}